// Round 1
// baseline (72.500 us; speedup 1.0000x reference)
//
#include <hip/hip_runtime.h>

#define S 256
#define NF 4096
#define TILE 16
#define NEARF 0.1f
#define FARF 100.0f
#define EPSF 1e-8f

// One block per 16x16 pixel tile. Phase A: conservative bbox + backface cull of
// all 4096 faces into an LDS candidate list. Phase B: each thread owns one
// pixel and scans the candidate list with bit-exact (non-fused, IEEE) fp32
// arithmetic replicating the numpy/jax reference. Tie-break (d==best && f<bestf)
// makes the result independent of the (atomic, unordered) compaction order.
__global__ __launch_bounds__(256) void raster_tile(const float* __restrict__ faces,
                                                   int* __restrict__ out) {
    __shared__ int s_ids[NF];
    __shared__ int s_count;

    const int tile = blockIdx.x;
    const int tx0 = (tile & (S / TILE - 1)) * TILE;
    const int ty0 = (tile / (S / TILE)) * TILE;

    if (threadIdx.x == 0) s_count = 0;
    __syncthreads();

    // Tile pixel-center bounds in NDC, with small safety margin against
    // ulp-level inside-test flips just outside the exact bbox.
    const float cxlo = (2.0f * tx0 + 1.0f - 256.0f) * (1.0f / 256.0f) - 1e-5f;
    const float cxhi = (2.0f * (tx0 + TILE - 1) + 1.0f - 256.0f) * (1.0f / 256.0f) + 1e-5f;
    const float cylo = (2.0f * ty0 + 1.0f - 256.0f) * (1.0f / 256.0f) - 1e-5f;
    const float cyhi = (2.0f * (ty0 + TILE - 1) + 1.0f - 256.0f) * (1.0f / 256.0f) + 1e-5f;

    // ---- Phase A: cull ----
    for (int f = threadIdx.x; f < NF; f += 256) {
        const float* p = faces + f * 9;
        const float x0 = p[0], y0 = p[1];
        const float x1 = p[3], y1 = p[4];
        const float x2 = p[6], y2 = p[7];
        const float bxmin = fminf(x0, fminf(x1, x2));
        const float bxmax = fmaxf(x0, fmaxf(x1, x2));
        const float bymin = fminf(y0, fminf(y1, y2));
        const float bymax = fmaxf(y0, fmaxf(y1, y2));
        bool hit = (bxmax >= cxlo) && (bxmin <= cxhi) && (bymax >= cylo) && (bymin <= cyhi);
        if (hit) {
            // w_sum (= 2*signed area) is constant per face up to fp32 noise
            // (~1e-6). Cull only when the exact (double) area is decisively
            // negative, so no pixel whose fp32 w_sum>0 can be lost.
            const double a2 = ((double)x1 - (double)x0) * ((double)y2 - (double)y0) -
                              ((double)x2 - (double)x0) * ((double)y1 - (double)y0);
            hit = (a2 > -1e-4);
        }
        if (hit) {
            const int pos = atomicAdd(&s_count, 1);
            s_ids[pos] = f;
        }
    }
    __syncthreads();
    const int n = s_count;

    // ---- Phase B: per-pixel scan of candidates ----
    const int lx = threadIdx.x & (TILE - 1);
    const int ly = threadIdx.x / TILE;
    const int px = tx0 + lx;
    const int py = ty0 + ly;
    // (2i+1-256)/256: odd numerator / pow2 -> exact in fp32.
    const float xp = (2.0f * px + 1.0f - 256.0f) * (1.0f / 256.0f);
    const float yp = (2.0f * py + 1.0f - 256.0f) * (1.0f / 256.0f);

    float bestd = FARF;
    int bestf = -1;

    for (int i = 0; i < n; ++i) {
        const int f = s_ids[i];
        const float* p = faces + f * 9;
        const float x0 = p[0], y0 = p[1], z0 = p[2];
        const float x1 = p[3], y1 = p[4], z1 = p[5];
        const float x2 = p[6], y2 = p[7], z2 = p[8];

        // Bit-exact replication: no fma contraction, exact association.
        const float w0 = __fsub_rn(__fmul_rn(__fsub_rn(yp, y1), __fsub_rn(x2, x1)),
                                   __fmul_rn(__fsub_rn(xp, x1), __fsub_rn(y2, y1)));
        const float w1 = __fsub_rn(__fmul_rn(__fsub_rn(yp, y2), __fsub_rn(x0, x2)),
                                   __fmul_rn(__fsub_rn(xp, x2), __fsub_rn(y0, y2)));
        const float w2 = __fsub_rn(__fmul_rn(__fsub_rn(yp, y0), __fsub_rn(x1, x0)),
                                   __fmul_rn(__fsub_rn(xp, x0), __fsub_rn(y1, y0)));

        const bool inside = (__fmul_rn(w0, w1) > 0.0f) && (__fmul_rn(w1, w2) > 0.0f);
        const float wsum = __fadd_rn(__fadd_rn(w0, w1), w2);

        if (inside && (wsum > 0.0f)) {
            float denom = __fadd_rn(__fadd_rn(__fdiv_rn(w0, z0), __fdiv_rn(w1, z1)),
                                    __fdiv_rn(w2, z2));
            denom = (fabsf(denom) > EPSF) ? denom : EPSF;
            const float zp = __fdiv_rn(wsum, denom);
            if ((zp > NEARF) && (zp < FARF)) {
                if (zp < bestd || (zp == bestd && f < bestf)) {
                    bestd = zp;
                    bestf = f;
                }
            }
        }
    }

    out[py * S + px] = bestf;
}

extern "C" void kernel_launch(void* const* d_in, const int* in_sizes, int n_in,
                              void* d_out, int out_size, void* d_ws, size_t ws_size,
                              hipStream_t stream) {
    const float* faces = (const float*)d_in[0];
    int* out = (int*)d_out;
    hipLaunchKernelGGL(raster_tile, dim3((S / TILE) * (S / TILE)), dim3(256), 0, stream,
                       faces, out);
}

// Round 2
// 30.123 us; speedup vs baseline: 2.4068x; 2.4068x over previous
//
#include <hip/hip_runtime.h>

#define S 256
#define NF 4096
#define TILE 16
#define NT 1024           // threads per block = 4 slices x 256 pixels
#define SLICES 4
#define CAP 1024          // candidate faces staged in LDS (overflow -> global path)
#define NEARF 0.1f
#define FARF 100.0f
#define EPSF 1e-8f

// One block per 16x16 pixel tile, 4 threads per pixel.
// Phase A (1024 threads): conservative bbox + backface cull of all 4096 faces,
// compacting id + vertex data into LDS.
// Phase B: each thread scans a 1/4 slice of the candidate list (LDS broadcast
// reads) with bit-exact fp32 math replicating the reference; partial results
// merge via an order-independent (depth_bits<<32 | face) min-key, which also
// implements the lowest-index-at-equal-depth tie-break, making the result
// independent of the atomic compaction order.
__global__ __launch_bounds__(NT) void raster_tile(const float* __restrict__ faces,
                                                  int* __restrict__ out) {
    __shared__ float4 s_data[CAP][3];
    __shared__ int s_ids[NF];
    __shared__ unsigned long long s_key[NT];
    __shared__ int s_count;

    const int tile = blockIdx.x;
    const int tx0 = (tile & (S / TILE - 1)) * TILE;
    const int ty0 = (tile / (S / TILE)) * TILE;

    if (threadIdx.x == 0) s_count = 0;
    __syncthreads();

    // Tile pixel-center bounds in NDC with margin vs ulp-level boundary flips.
    const float cxlo = (2.0f * tx0 + 1.0f - 256.0f) * (1.0f / 256.0f) - 1e-5f;
    const float cxhi = (2.0f * (tx0 + TILE - 1) + 1.0f - 256.0f) * (1.0f / 256.0f) + 1e-5f;
    const float cylo = (2.0f * ty0 + 1.0f - 256.0f) * (1.0f / 256.0f) - 1e-5f;
    const float cyhi = (2.0f * (ty0 + TILE - 1) + 1.0f - 256.0f) * (1.0f / 256.0f) + 1e-5f;

    // ---- Phase A: cull + compact data into LDS ----
    for (int f = threadIdx.x; f < NF; f += NT) {
        const float* p = faces + f * 9;
        const float x0 = p[0], y0 = p[1], z0 = p[2];
        const float x1 = p[3], y1 = p[4], z1 = p[5];
        const float x2 = p[6], y2 = p[7], z2 = p[8];
        const float bxmin = fminf(x0, fminf(x1, x2));
        const float bxmax = fmaxf(x0, fmaxf(x1, x2));
        const float bymin = fminf(y0, fminf(y1, y2));
        const float bymax = fmaxf(y0, fmaxf(y1, y2));
        bool hit = (bxmax >= cxlo) && (bxmin <= cxhi) && (bymax >= cylo) && (bymin <= cyhi);
        if (hit) {
            // 2*signed area in double; cull only when decisively negative so no
            // pixel whose fp32 w_sum>0 can be lost (fp32 noise ~1e-6 << 1e-4).
            const double a2 = ((double)x1 - (double)x0) * ((double)y2 - (double)y0) -
                              ((double)x2 - (double)x0) * ((double)y1 - (double)y0);
            hit = (a2 > -1e-4);
        }
        if (hit) {
            const int pos = atomicAdd(&s_count, 1);
            s_ids[pos] = f;
            if (pos < CAP) {
                s_data[pos][0] = make_float4(x0, y0, x1, y1);
                s_data[pos][1] = make_float4(x2, y2, z0, z1);
                s_data[pos][2] = make_float4(z2, __int_as_float(f), 0.0f, 0.0f);
            }
        }
    }
    __syncthreads();
    const int n = s_count;
    const int nc = n < CAP ? n : CAP;

    // ---- Phase B: sliced per-pixel scan ----
    const int pix = threadIdx.x & 255;
    const int slice = threadIdx.x >> 8;          // wave-uniform (64 | 256)
    const int px = tx0 + (pix & (TILE - 1));
    const int py = ty0 + (pix / TILE);
    // (2i+1-256)/256: odd numerator / pow2 -> exact in fp32.
    const float xp = (2.0f * px + 1.0f - 256.0f) * (1.0f / 256.0f);
    const float yp = (2.0f * py + 1.0f - 256.0f) * (1.0f / 256.0f);

    float bestd = FARF;
    int bestf = 0x7fffffff;

#define BODY(X0, Y0, Z0, X1, Y1, Z1, X2, Y2, Z2, FIDX)                                   \
    {                                                                                    \
        const float w0 = __fsub_rn(__fmul_rn(__fsub_rn(yp, Y1), __fsub_rn(X2, X1)),      \
                                   __fmul_rn(__fsub_rn(xp, X1), __fsub_rn(Y2, Y1)));     \
        const float w1 = __fsub_rn(__fmul_rn(__fsub_rn(yp, Y2), __fsub_rn(X0, X2)),      \
                                   __fmul_rn(__fsub_rn(xp, X2), __fsub_rn(Y0, Y2)));     \
        const float w2 = __fsub_rn(__fmul_rn(__fsub_rn(yp, Y0), __fsub_rn(X1, X0)),      \
                                   __fmul_rn(__fsub_rn(xp, X0), __fsub_rn(Y1, Y0)));     \
        const bool inside = (__fmul_rn(w0, w1) > 0.0f) && (__fmul_rn(w1, w2) > 0.0f);    \
        const float wsum = __fadd_rn(__fadd_rn(w0, w1), w2);                             \
        if (inside && (wsum > 0.0f)) {                                                   \
            float denom = __fadd_rn(__fadd_rn(__fdiv_rn(w0, Z0), __fdiv_rn(w1, Z1)),     \
                                    __fdiv_rn(w2, Z2));                                  \
            denom = (fabsf(denom) > EPSF) ? denom : EPSF;                                \
            const float zp = __fdiv_rn(wsum, denom);                                     \
            if ((zp > NEARF) && (zp < FARF)) {                                           \
                if (zp < bestd || (zp == bestd && (FIDX) < bestf)) {                     \
                    bestd = zp;                                                          \
                    bestf = (FIDX);                                                      \
                }                                                                        \
            }                                                                            \
        }                                                                                \
    }

    for (int i = slice; i < nc; i += SLICES) {
        const float4 d0 = s_data[i][0];
        const float4 d1 = s_data[i][1];
        const float4 d2 = s_data[i][2];
        const int f = __float_as_int(d2.y);
        BODY(d0.x, d0.y, d1.z, d0.z, d0.w, d1.w, d1.x, d1.y, d2.x, f)
    }
    // Overflow path (n > CAP): statistically never taken (n ~ 80), but correct.
    for (int i = CAP + slice; i < n; i += SLICES) {
        const int f = s_ids[i];
        const float* p = faces + f * 9;
        BODY(p[0], p[1], p[2], p[3], p[4], p[5], p[6], p[7], p[8], f)
    }
#undef BODY

    // ---- Merge 4 slices per pixel via packed min-key ----
    s_key[threadIdx.x] =
        ((unsigned long long)__float_as_uint(bestd) << 32) | (unsigned int)bestf;
    __syncthreads();
    if (threadIdx.x < 256) {
        unsigned long long k = s_key[threadIdx.x];
        unsigned long long k1 = s_key[threadIdx.x + 256];
        unsigned long long k2 = s_key[threadIdx.x + 512];
        unsigned long long k3 = s_key[threadIdx.x + 768];
        k = k1 < k ? k1 : k;
        k = k2 < k ? k2 : k;
        k = k3 < k ? k3 : k;
        const float d = __uint_as_float((unsigned int)(k >> 32));
        const int fi = (int)(unsigned int)k;
        const int opx = tx0 + (threadIdx.x & (TILE - 1));
        const int opy = ty0 + (threadIdx.x / TILE);
        out[opy * S + opx] = (d < FARF) ? fi : -1;
    }
}

extern "C" void kernel_launch(void* const* d_in, const int* in_sizes, int n_in,
                              void* d_out, int out_size, void* d_ws, size_t ws_size,
                              hipStream_t stream) {
    const float* faces = (const float*)d_in[0];
    int* out = (int*)d_out;
    hipLaunchKernelGGL(raster_tile, dim3((S / TILE) * (S / TILE)), dim3(NT), 0, stream,
                       faces, out);
}